// Round 7
// baseline (210.787 us; speedup 1.0000x reference)
//
#include <hip/hip_runtime.h>
#include <math.h>

static constexpr int BROWS   = 16384;
static constexpr int NC      = 784;
static constexpr int TRB     = 16;              // rows per tile/block
static constexpr int THREADS = 256;
static constexpr int NTILE   = BROWS / TRB;     // 1024 tiles (= persistent grid)
static constexpr int NSLOT   = 4;               // ceil(784/256) column slots per thread
static constexpr int NREP    = 4;               // replicated stat accumulators
static constexpr float EPS   = 1e-5f;
static constexpr float INV_B = 1.0f / (float)BROWS;

#if defined(__has_builtin)
#if __has_builtin(__builtin_amdgcn_global_load_lds)
#define HAVE_ASYNC_LDS 1
#endif
#if __has_builtin(__builtin_amdgcn_rcpf)
#define HAVE_RCPF 1
#endif
#endif

__device__ __forceinline__ void stage16(const float4* g, float4* l) {
#ifdef HAVE_ASYNC_LDS
    __builtin_amdgcn_global_load_lds(
        (const __attribute__((address_space(1))) void*)g,
        (__attribute__((address_space(3))) void*)l, 16, 0, 0);
#else
    *l = *g;
#endif
}

// ---- bf16 helpers (raw u16 storage; RNE convert) ----
__device__ __forceinline__ unsigned short f2b(float f) {
    union { float f; unsigned u; } v; v.f = f;
    const unsigned r = v.u + 0x7fffu + ((v.u >> 16) & 1u);
    return (unsigned short)(r >> 16);
}
__device__ __forceinline__ unsigned pack2(float lo, float hi) {
    return (unsigned)f2b(lo) | ((unsigned)f2b(hi) << 16);
}
__device__ __forceinline__ unsigned long long pack4(float a, float b, float c, float d) {
    return (unsigned long long)pack2(a, b) | ((unsigned long long)pack2(c, d) << 32);
}
// u64 = 4 bf16 rows of one column
__device__ __forceinline__ void unpack4(unsigned long long v, float f[4]) {
    const unsigned lo = (unsigned)v, hi = (unsigned)(v >> 32);
    union { unsigned u; float f; } a, b, c, d;
    a.u = lo << 16; b.u = lo & 0xffff0000u; c.u = hi << 16; d.u = hi & 0xffff0000u;
    f[0] = a.f; f[1] = b.f; f[2] = c.f; f[3] = d.f;
}

__device__ __forceinline__ float fast_rcp(float x) {
#ifdef HAVE_RCPF
    return __builtin_amdgcn_rcpf(x);
#else
    return 1.0f / x;
#endif
}

// Exact-accuracy gelu via A&S 7.1.26 erf (|eps| <= 1.5e-7), branchless. (validated R4/R6)
__device__ __forceinline__ float gelu_f(float x) {
    const float a = fabsf(x) * 0.7071067811865475f;
    const float t = fast_rcp(fmaf(0.3275911f, a, 1.0f));
    float p = fmaf(t, 1.061405429f, -1.453152027f);
    p = fmaf(t, p, 1.421413741f);
    p = fmaf(t, p, -0.284496736f);
    p = fmaf(t, p, 0.254829592f);
    p *= t;
    const float e  = __expf(-a * a);
    const float er = fmaf(-p, e, 1.0f);
    return 0.5f * x * (1.0f + copysignf(er, x));
}

// ---- stage 16 fp32 rows of x into the quad-interleaved bf16 LDS tile ----
__device__ __forceinline__ void stage_x(const float* __restrict__ x,
                                        unsigned long long* quad, int row0) {
    const int tid = threadIdx.x;
    #pragma unroll
    for (int slot = 0; slot < NSLOT; ++slot) {
        const int c = tid + slot * THREADS;
        if (c < NC) {
            #pragma unroll
            for (int q = 0; q < 4; ++q) {
                const size_t base = (size_t)(row0 + 4 * q) * NC + c;
                quad[q * NC + c] = pack4(x[base], x[base + NC], x[base + 2 * NC], x[base + 3 * NC]);
            }
        }
    }
    __syncthreads();
}

// ---- finalize a BN from replicated accumulators into LDS scale/shift ----
// psum/psq read with agent-scope atomic loads (XCD-L2-coherence safe).
__device__ __forceinline__ void make_scsh(const float* __restrict__ psum,
                                          const float* __restrict__ psq,
                                          const float* __restrict__ gamma,
                                          const float* __restrict__ beta,
                                          float* s_sc, float* s_sh) {
    const int tid = threadIdx.x;
    for (int j = tid; j < NC; j += THREADS) {
        float s1 = 0.0f, s2 = 0.0f;
        #pragma unroll
        for (int r = 0; r < NREP; ++r) {
            s1 += __hip_atomic_load(&psum[r * NC + j], __ATOMIC_RELAXED, __HIP_MEMORY_SCOPE_AGENT);
            s2 += __hip_atomic_load(&psq[r * NC + j],  __ATOMIC_RELAXED, __HIP_MEMORY_SCOPE_AGENT);
        }
        const float m   = s1 * INV_B;
        const float var = fmaf(-m, m, s2 * INV_B);
        const float sc  = gamma[j] * rsqrtf(var + EPS);
        s_sc[j] = sc;
        s_sh[j] = fmaf(-m, sc, beta[j]);
    }
    __syncthreads();
}

// ---- one sparse layer, in-place on the LDS quad tile (two 8-row halves) ----
template<int K, bool FOLD, bool STATS>
__device__ __forceinline__ void do_layer(unsigned long long* quad,
                                         const float* s_sc, const float* s_sh,
                                         const int* __restrict__ idx,
                                         const float* __restrict__ W,
                                         const float* __restrict__ bias,
                                         float* __restrict__ ssum,
                                         float* __restrict__ ssq, int rep) {
    const int tid = threadIdx.x;
    float st1[NSLOT], st2[NSLOT];
    if (STATS)
        #pragma unroll
        for (int s = 0; s < NSLOT; ++s) { st1[s] = 0.0f; st2[s] = 0.0f; }

    for (int half = 0; half < 2; ++half) {
        float outv[NSLOT][8];
        #pragma unroll
        for (int slot = 0; slot < NSLOT; ++slot) {
            const int j = tid + slot * THREADS;
            if (j < NC) {
                int ji[K]; float jw[K];
                float jb = bias[j];
                #pragma unroll
                for (int k = 0; k < K; ++k) {
                    const int   c = idx[j * K + k];
                    const float w = W[j * K + k];
                    ji[k] = c;
                    if (FOLD) { jw[k] = w * s_sc[c]; jb = fmaf(w, s_sh[c], jb); }
                    else        jw[k] = w;
                }
                float acc[8];
                #pragma unroll
                for (int r = 0; r < 8; ++r) acc[r] = jb;
                #pragma unroll
                for (int k = 0; k < K; ++k) {
                    #pragma unroll
                    for (int qq = 0; qq < 2; ++qq) {
                        float f[4];
                        unpack4(quad[(2 * half + qq) * NC + ji[k]], f);
                        #pragma unroll
                        for (int rr = 0; rr < 4; ++rr)
                            acc[qq * 4 + rr] = fmaf(f[rr], jw[k], acc[qq * 4 + rr]);
                    }
                }
                #pragma unroll
                for (int r = 0; r < 8; ++r) {
                    const float u = gelu_f(acc[r]);
                    outv[slot][r] = u;
                    if (STATS) { st1[slot] += u; st2[slot] = fmaf(u, u, st2[slot]); }
                }
            }
        }
        __syncthreads();                 // all gathers of this half done
        #pragma unroll
        for (int slot = 0; slot < NSLOT; ++slot) {
            const int j = tid + slot * THREADS;
            if (j < NC) {
                quad[(2 * half + 0) * NC + j] = pack4(outv[slot][0], outv[slot][1], outv[slot][2], outv[slot][3]);
                quad[(2 * half + 1) * NC + j] = pack4(outv[slot][4], outv[slot][5], outv[slot][6], outv[slot][7]);
            }
        }
        __syncthreads();
    }
    if (STATS) {
        #pragma unroll
        for (int slot = 0; slot < NSLOT; ++slot) {
            const int j = tid + slot * THREADS;
            if (j < NC) {
                atomicAdd(&ssum[rep * NC + j], st1[slot]);
                atomicAdd(&ssq[rep * NC + j],  st2[slot]);
            }
        }
    }
}

// ---- final layer: fold bn2b, K=2, relu, fp32 row-major store ----
__device__ __forceinline__ void do_final(const unsigned long long* quad,
                                         const float* s_sc, const float* s_sh,
                                         const int* __restrict__ idx,
                                         const float* __restrict__ W,
                                         const float* __restrict__ bias,
                                         float* __restrict__ out, int row0) {
    const int tid = threadIdx.x;
    #pragma unroll
    for (int slot = 0; slot < NSLOT; ++slot) {
        const int j = tid + slot * THREADS;
        if (j < NC) {
            const int   c0 = idx[2 * j], c1 = idx[2 * j + 1];
            const float w0 = W[2 * j],   w1 = W[2 * j + 1];
            const float jw0 = w0 * s_sc[c0], jw1 = w1 * s_sc[c1];
            const float jb  = fmaf(w0, s_sh[c0], fmaf(w1, s_sh[c1], bias[j]));
            #pragma unroll
            for (int q = 0; q < 4; ++q) {
                float f0[4], f1[4];
                unpack4(quad[q * NC + c0], f0);
                unpack4(quad[q * NC + c1], f1);
                #pragma unroll
                for (int rr = 0; rr < 4; ++rr) {
                    const float acc = fmaf(f0[rr], jw0, fmaf(f1[rr], jw1, jb));
                    out[(size_t)(row0 + 4 * q + rr) * NC + j] = fmaxf(acc, 0.0f);
                }
            }
        }
    }
}

// ---- grid barrier: sense via monotone generation counter ----
__device__ __forceinline__ void grid_barrier(unsigned* cnt, unsigned* gen, unsigned target) {
    __syncthreads();
    if (threadIdx.x == 0) {
        __threadfence();
        const unsigned old = __hip_atomic_fetch_add(cnt, 1u, __ATOMIC_ACQ_REL, __HIP_MEMORY_SCOPE_AGENT);
        if (old == (unsigned)NTILE - 1u) {
            __hip_atomic_fetch_add(gen, 1u, __ATOMIC_RELEASE, __HIP_MEMORY_SCOPE_AGENT);
        } else {
            while (__hip_atomic_load(gen, __ATOMIC_ACQUIRE, __HIP_MEMORY_SCOPE_AGENT) < target)
                __builtin_amdgcn_s_sleep(2);
        }
        __threadfence();
    }
    __syncthreads();
}

// ================= persistent whole-net kernel (grid must be exactly NTILE) =================
__global__ __launch_bounds__(THREADS, 4)
void persist(const float* __restrict__ x,
             const int* __restrict__ idx1, const float* __restrict__ W1, const float* __restrict__ b1,
             const int* __restrict__ idx2, const float* __restrict__ W2, const float* __restrict__ b2,
             const int* __restrict__ idx3, const float* __restrict__ W3, const float* __restrict__ b3,
             const float* __restrict__ g2, const float* __restrict__ be2,
             const float* __restrict__ g3, const float* __restrict__ be3,
             float* __restrict__ out,
             float* __restrict__ sum2a, float* __restrict__ ssq2a,
             float* __restrict__ sum3,  float* __restrict__ ssq3,
             float* __restrict__ sum2b, float* __restrict__ ssq2b,
             unsigned* __restrict__ bar)          // [cnt0,cnt1,cnt2,gen]
{
    __shared__ __align__(16) unsigned long long quad[4 * NC];  // 25088 B
    __shared__ float s_sc[NC], s_sh[NC];                       //  6272 B
    const int row0 = blockIdx.x * TRB;
    const int rep  = blockIdx.x & (NREP - 1);

    stage_x(x, quad, row0);
    do_layer<2, false, false>(quad, s_sc, s_sh, idx1, W1, b1, nullptr, nullptr, rep); // L1
    do_layer<4, false, true >(quad, s_sc, s_sh, idx2, W2, b2, sum2a, ssq2a, rep);     // L2 + stats
    grid_barrier(bar + 0, bar + 3, 1u);
    make_scsh(sum2a, ssq2a, g2, be2, s_sc, s_sh);
    do_layer<8, true,  true >(quad, s_sc, s_sh, idx3, W3, b3, sum3, ssq3, rep);       // L3 + stats
    grid_barrier(bar + 1, bar + 3, 2u);
    make_scsh(sum3, ssq3, g3, be3, s_sc, s_sh);
    do_layer<4, true,  true >(quad, s_sc, s_sh, idx2, W2, b2, sum2b, ssq2b, rep);     // L4 + stats
    grid_barrier(bar + 2, bar + 3, 3u);
    make_scsh(sum2b, ssq2b, g2, be2, s_sc, s_sh);
    do_final(quad, s_sc, s_sh, idx1, W1, b1, out, row0);                               // L5
}

// ================= fallback: proven 4-kernel pipeline (same device functions) =================
__global__ __launch_bounds__(THREADS, 4)
void fb_layer12(const float* __restrict__ x,
                const int* __restrict__ idx1, const float* __restrict__ W1, const float* __restrict__ b1,
                const int* __restrict__ idx2, const float* __restrict__ W2, const float* __restrict__ b2,
                unsigned long long* __restrict__ uqout,
                float* __restrict__ ssum, float* __restrict__ ssq)
{
    __shared__ __align__(16) unsigned long long quad[4 * NC];
    const int row0 = blockIdx.x * TRB;
    const int rep  = blockIdx.x & (NREP - 1);
    stage_x(x, quad, row0);
    do_layer<2, false, false>(quad, nullptr, nullptr, idx1, W1, b1, nullptr, nullptr, rep);
    do_layer<4, false, true >(quad, nullptr, nullptr, idx2, W2, b2, ssum, ssq, rep);
    for (int i = threadIdx.x; i < 4 * NC; i += THREADS)
        uqout[(size_t)blockIdx.x * 4 * NC + i] = quad[i];
}

template<int K, bool FINAL>
__global__ __launch_bounds__(THREADS, 4)
void fb_layer_bn(const unsigned long long* __restrict__ uqin,
                 const int* __restrict__ idx, const float* __restrict__ W, const float* __restrict__ bias,
                 const float* __restrict__ gamma, const float* __restrict__ beta,
                 const float* __restrict__ psum, const float* __restrict__ psq,
                 unsigned long long* __restrict__ uqout, float* __restrict__ fout,
                 float* __restrict__ ssum, float* __restrict__ ssq)
{
    __shared__ __align__(16) unsigned long long quad[4 * NC];
    __shared__ float s_sc[NC], s_sh[NC];
    const int row0 = blockIdx.x * TRB;
    const int rep  = blockIdx.x & (NREP - 1);
    {
        const float4* src = (const float4*)(uqin + (size_t)blockIdx.x * 4 * NC);
        float4*       dst = (float4*)quad;
        for (int i = threadIdx.x; i < 4 * NC / 2; i += THREADS) stage16(src + i, dst + i);
    }
    make_scsh(psum, psq, gamma, beta, s_sc, s_sh);   // its __syncthreads drains the DMA
    if (FINAL) {
        do_final(quad, s_sc, s_sh, idx, W, bias, fout, row0);
    } else {
        do_layer<K, true, true>(quad, s_sc, s_sh, idx, W, bias, ssum, ssq, rep);
        for (int i = threadIdx.x; i < 4 * NC; i += THREADS)
            uqout[(size_t)blockIdx.x * 4 * NC + i] = quad[i];
    }
}

extern "C" void kernel_launch(void* const* d_in, const int* in_sizes, int n_in,
                              void* d_out, int out_size, void* d_ws, size_t ws_size,
                              hipStream_t stream)
{
    const float* x    = (const float*)d_in[0];
    const int*   idx1 = (const int*)  d_in[1];
    const float* W1   = (const float*)d_in[2];
    const float* b1   = (const float*)d_in[3];
    const int*   idx2 = (const int*)  d_in[4];
    const float* W2   = (const float*)d_in[5];
    const float* b2   = (const float*)d_in[6];
    const int*   idx3 = (const int*)  d_in[7];
    const float* W3   = (const float*)d_in[8];
    const float* b3   = (const float*)d_in[9];
    const float* g2   = (const float*)d_in[10];
    const float* be2  = (const float*)d_in[11];
    const float* g3   = (const float*)d_in[12];
    const float* be3  = (const float*)d_in[13];
    float* out = (float*)d_out;

    const size_t QN = (size_t)NTILE * 4 * NC;      // u64 elems per intermediate (fallback only)
    unsigned long long* ws0 = (unsigned long long*)d_ws;
    unsigned long long* ws1 = ws0 + QN;
    float* p = (float*)(ws1 + QN);
    float* sum2a = p; p += NREP * NC;  float* ssq2a = p; p += NREP * NC;
    float* sum3  = p; p += NREP * NC;  float* ssq3  = p; p += NREP * NC;
    float* sum2b = p; p += NREP * NC;  float* ssq2b = p; p += NREP * NC;
    unsigned* bar = (unsigned*)p;                  // [cnt0,cnt1,cnt2,gen]

    // zero stats + barrier words (ws is poisoned 0xAA before every call)
    hipMemsetAsync(sum2a, 0, 6 * NREP * NC * sizeof(float) + 4 * sizeof(unsigned), stream);

    // Deterministic host-side co-residency check (same result every call; graph-safe).
    int maxBlk = 0;
    const hipError_t qerr =
        hipOccupancyMaxActiveBlocksPerMultiprocessor(&maxBlk, (const void*)persist, THREADS, 0);
    const bool resident = (qerr == hipSuccess && maxBlk >= 4);   // 4/CU * 256 CUs = 1024 blocks

    if (resident) {
        persist<<<dim3(NTILE), dim3(THREADS), 0, stream>>>(
            x, idx1, W1, b1, idx2, W2, b2, idx3, W3, b3,
            g2, be2, g3, be3, out,
            sum2a, ssq2a, sum3, ssq3, sum2b, ssq2b, bar);
    } else {
        const dim3 grid(NTILE), blk(THREADS);
        fb_layer12<<<grid, blk, 0, stream>>>(x, idx1, W1, b1, idx2, W2, b2, ws0, sum2a, ssq2a);
        fb_layer_bn<8, false><<<grid, blk, 0, stream>>>(
            ws0, idx3, W3, b3, g2, be2, sum2a, ssq2a, ws1, nullptr, sum3, ssq3);
        fb_layer_bn<4, false><<<grid, blk, 0, stream>>>(
            ws1, idx2, W2, b2, g3, be3, sum3, ssq3, ws0, nullptr, sum2b, ssq2b);
        fb_layer_bn<2, true><<<grid, blk, 0, stream>>>(
            ws0, idx1, W1, b1, g2, be2, sum2b, ssq2b, nullptr, out, nullptr, nullptr);
    }
}